// Round 2
// baseline (329.605 us; speedup 1.0000x reference)
//
#include <hip/hip_runtime.h>
#include <cstdint>

#define M_DIM 65536
#define N_DIM 512
#define K_DIM 512
#define BM 128
#define BN 128
#define BK 32
#define KSTEPS (K_DIM / BK)

typedef float f32x4 __attribute__((ext_vector_type(4)));
typedef __bf16 bf16x8 __attribute__((ext_vector_type(8)));
typedef unsigned short us8 __attribute__((ext_vector_type(8)));

__device__ __forceinline__ unsigned short f2bf(float f) {
  unsigned int u = __builtin_bit_cast(unsigned int, f);
  u += 0x7fffu + ((u >> 16) & 1u);  // round-to-nearest-even
  return (unsigned short)(u >> 16);
}

// ---------------------------------------------------------------------------
// Prep: WCT2[(kq*512 + (o*8+kb))*8 + i] = bf16(wc[i][kb]) for (o, n_in=kq).
// k-dim index = n_in*8 + i, so kq = k/8, i = k%8. This layout makes the GEMM's
// B-fragment load one coalesced 16B global load per lane (L2-resident).
//       bias2[o*8+k] = bias[o,k] + (k==0)*bias_shift[o]
// ---------------------------------------------------------------------------
__global__ void clifford_prep(const float* __restrict__ weight,
                              const float* __restrict__ bias,
                              const float* __restrict__ row_scale,
                              const float* __restrict__ col_scale,
                              const float* __restrict__ bias_shift,
                              unsigned short* __restrict__ WCT2,
                              float* __restrict__ bias2) {
  const int t = blockIdx.x * 256 + threadIdx.x;
  if (t < 512) {
    const int o = t >> 3, k = t & 7;
    bias2[t] = bias[t] + (k == 0 ? bias_shift[o] : 0.0f);
  }
  if (t >= 64 * 64) return;
  const int o = t >> 6, n = t & 63;  // n = input feature = kq
  const float rs = row_scale[o], cs = col_scale[n];
  float w[8];
#pragma unroll
  for (int j = 0; j < 8; ++j) {
    float v = weight[(size_t)t * 8 + j] * rs * cs;
    w[j] = (v != v) ? 0.0f : v;  // nan_to_num
  }
  constexpr int TI[64] = {0,1,2,3,4,5,6,7, 0,1,2,4,3,5,6,7, 0,2,1,4,3,6,5,7,
                          0,3,1,5,2,6,4,7, 0,4,1,2,3,7,5,6, 0,5,1,3,2,7,4,6,
                          0,6,2,3,1,7,4,5, 0,7,1,6,2,5,3,4};
  constexpr int TJ[64] = {0,1,2,3,4,5,6,7, 1,0,4,2,5,3,7,6, 2,0,4,1,6,3,7,5,
                          3,0,5,1,6,2,7,4, 4,0,2,1,7,3,6,5, 5,0,3,1,7,2,6,4,
                          6,0,3,2,7,1,5,4, 7,0,6,1,5,2,4,3};
  constexpr int TK[64] = {0,0,0,0,0,0,0,0, 1,1,1,1,1,1,1,1, 2,2,2,2,2,2,2,2,
                          3,3,3,3,3,3,3,3, 4,4,4,4,4,4,4,4, 5,5,5,5,5,5,5,5,
                          6,6,6,6,6,6,6,6, 7,7,7,7,7,7,7,7};
  constexpr float TS[64] = {1,1,1,1,-1,-1,-1,-1, 1,1,-1,1,-1,1,-1,-1, 1,1,1,-1,-1,1,1,1,
                            1,1,1,-1,1,-1,-1,-1, 1,1,1,-1,1,1,-1,1,  1,1,1,-1,-1,-1,1,-1,
                            1,1,1,-1,1,1,-1,1,   1,1,1,1,-1,-1,1,1};
  float wc[8][8];
#pragma unroll
  for (int i = 0; i < 8; ++i)
#pragma unroll
    for (int k = 0; k < 8; ++k) wc[i][k] = 0.0f;
#pragma unroll
  for (int e = 0; e < 64; ++e) wc[TI[e]][TK[e]] += TS[e] * w[TJ[e]];
  // WCT2 layout: [kq=n][nOut=o*8+kb][i]
#pragma unroll
  for (int kb = 0; kb < 8; ++kb)
#pragma unroll
    for (int i = 0; i < 8; ++i)
      WCT2[((size_t)n * N_DIM + o * 8 + kb) * 8 + i] = f2bf(wc[i][kb]);
}

// ---------------------------------------------------------------------------
// GEMM: out[M,N] = x[M,K] * W^T (+ bias2). NO LDS, NO BARRIERS.
// A fragments load directly from global (lane (lm,kg) reads 32 contiguous
// bytes of row wm+mi*16+lm; a wave covers 16 rows x 128B -> coalesced), then
// f32->bf16 scalar casts in registers. B direct from L2-resident WCT2.
// Depth-1 software pipeline: cvt A(ks) frees the single A f32 buffer, then
// issue A(ks+1)+B(ks+1), then MFMA(ks). Waves are fully independent ->
// HBM latency hidden by prefetch + co-resident blocks, not a barrier.
// XCD swizzle keeps the 4 n-tiles of an m-tile on one XCD for x L2 reuse
// (wave pairs within a block read the same x rows 2x -> L2 absorbs).
// ---------------------------------------------------------------------------
__global__ __launch_bounds__(256, 3) void clifford_gemm(
    const float* __restrict__ x, const unsigned short* __restrict__ WCT2,
    const float* __restrict__ bias2, float* __restrict__ out) {
  const int tid = threadIdx.x;
  const int lane = tid & 63;
  const int wv = tid >> 6;

  const int bid = blockIdx.x;
  const int grp = bid >> 5, r = bid & 31;
  const size_t m0 = (size_t)(grp * 8 + (r & 7)) * BM;
  const int n0 = (r >> 3) * BN;

  // fragment geometry (16x16x32: A[m=lane&15][k=(lane>>4)*8+j])
  const int wm = (wv & 1) * 64;
  const int wn = (wv >> 1) * 64;
  const int lm = lane & 15;
  const int kg = lane >> 4;  // 0..3

  // A per-fragment global base: row (m0+wm+mi*16+lm), k-offset kg*8.
  // Per k-step advance is 32 floats = 128 B -> folds into the 13-bit imm.
  const float* am[4];
#pragma unroll
  for (int mi = 0; mi < 4; ++mi)
    am[mi] = x + (m0 + wm + mi * 16 + lm) * (size_t)K_DIM + kg * 8;

  // B per-lane base (elements). fragment ni at +ni*128; k-step at +4*N_DIM*8.
  const unsigned short* bg = WCT2 + ((size_t)kg * N_DIM + (n0 + wn + lm)) * 8;

  const f32x4 zero = {0.f, 0.f, 0.f, 0.f};
  f32x4 acc[4][4];
#pragma unroll
  for (int i = 0; i < 4; ++i)
#pragma unroll
    for (int j = 0; j < 4; ++j) acc[i][j] = zero;

  f32x4 a[4][2];  // single f32 A buffer (freed by cvt before next issue)
  us8 b0[4], b1[4];

  auto loadA = [&](int ks) {
#pragma unroll
    for (int mi = 0; mi < 4; ++mi) {
      a[mi][0] = *(const f32x4*)(am[mi] + ks * BK);
      a[mi][1] = *(const f32x4*)(am[mi] + ks * BK + 4);
    }
  };
  auto loadB = [&](us8 (&bb)[4], int ks) {
    const unsigned short* p = bg + (size_t)ks * (4 * N_DIM * 8);
#pragma unroll
    for (int ni = 0; ni < 4; ++ni) bb[ni] = *(const us8*)(p + ni * 128);
  };
  auto cvtA = [&](bf16x8 (&af)[4]) {
#pragma unroll
    for (int mi = 0; mi < 4; ++mi) {
      bf16x8 t;
#pragma unroll
      for (int j = 0; j < 4; ++j) {
        t[j] = (__bf16)a[mi][0][j];
        t[4 + j] = (__bf16)a[mi][1][j];
      }
      af[mi] = t;
    }
  };

  // prologue
  loadA(0);
  loadB(b0, 0);

  auto body = [&](int ks, us8 (&bc)[4], us8 (&bn)[4]) {
    bf16x8 af[4];
    cvtA(af);  // waits vmcnt for A(ks); frees a[] for next issue
    if (ks < KSTEPS - 1) {
      loadA(ks + 1);
      loadB(bn, ks + 1);
    }
#pragma unroll
    for (int mi = 0; mi < 4; ++mi)
#pragma unroll
      for (int ni = 0; ni < 4; ++ni)
        acc[mi][ni] = __builtin_amdgcn_mfma_f32_16x16x32_bf16(
            af[mi], __builtin_bit_cast(bf16x8, bc[ni]), acc[mi][ni], 0, 0, 0);
  };

  // 2x-unrolled so B double-buffer indices are compile-time (no scratch)
  for (int ks2 = 0; ks2 < KSTEPS; ks2 += 2) {
    body(ks2, b0, b1);
    body(ks2 + 1, b1, b0);
  }

  // epilogue: C/D layout col=lane&15 (n), row=(lane>>4)*4+reg (m)
#pragma unroll
  for (int ni = 0; ni < 4; ++ni) {
    const int nn = n0 + wn + ni * 16 + lm;
    const float b2 = bias2[nn];
#pragma unroll
    for (int mi = 0; mi < 4; ++mi) {
#pragma unroll
      for (int rr = 0; rr < 4; ++rr) {
        const size_t mm = m0 + wm + mi * 16 + kg * 4 + rr;
        out[mm * N_DIM + nn] = acc[mi][ni][rr] + b2;
      }
    }
  }
}

extern "C" void kernel_launch(void* const* d_in, const int* in_sizes, int n_in,
                              void* d_out, int out_size, void* d_ws, size_t ws_size,
                              hipStream_t stream) {
  const float* x          = (const float*)d_in[0];
  const float* weight     = (const float*)d_in[1];
  const float* bias       = (const float*)d_in[2];
  const float* row_scale  = (const float*)d_in[3];
  const float* col_scale  = (const float*)d_in[4];
  const float* bias_shift = (const float*)d_in[5];

  unsigned short* WCT2 = (unsigned short*)d_ws;                      // 512*512*2 B
  float* bias2 = (float*)((char*)d_ws + (size_t)N_DIM * K_DIM * 2);  // +2 KB

  clifford_prep<<<16, 256, 0, stream>>>(weight, bias, row_scale, col_scale,
                                        bias_shift, WCT2, bias2);
  clifford_gemm<<<(M_DIM / BM) * (N_DIM / BN), 256, 0, stream>>>(
      x, WCT2, bias2, (float*)d_out);
}

// Round 3
// 289.988 us; speedup vs baseline: 1.1366x; 1.1366x over previous
//
#include <hip/hip_runtime.h>
#include <cstdint>

#define M_DIM 65536
#define N_DIM 512
#define K_DIM 512
#define BM 128
#define BN 128
#define BK 32
#define KSTEPS (K_DIM / BK)
// LDS: per-wave-private A tile, kb-slab layout. Slab = 64 rows * 8 shorts + 8 pad.
#define KBS 520
#define WREG (4 * KBS)  // 2080 shorts per wave-buffer

typedef float f32x4 __attribute__((ext_vector_type(4)));
typedef __bf16 bf16x8 __attribute__((ext_vector_type(8)));
typedef unsigned short us8 __attribute__((ext_vector_type(8)));

__device__ __forceinline__ unsigned short f2bf(float f) {
  unsigned int u = __builtin_bit_cast(unsigned int, f);
  u += 0x7fffu + ((u >> 16) & 1u);  // round-to-nearest-even
  return (unsigned short)(u >> 16);
}

// packed f32x2 -> bf16x2 (RNE), 1 VALU op for 2 elements
__device__ __forceinline__ unsigned int cvt_pk_bf16(float lo, float hi) {
  unsigned int r;
  asm("v_cvt_pk_bf16_f32 %0, %1, %2" : "=v"(r) : "v"(lo), "v"(hi));
  return r;
}

// ---------------------------------------------------------------------------
// Prep: WCT2[(kq*512 + (o*8+kb))*8 + i] = bf16(wc[i][kb]) for (o, n_in=kq).
// ---------------------------------------------------------------------------
__global__ void clifford_prep(const float* __restrict__ weight,
                              const float* __restrict__ bias,
                              const float* __restrict__ row_scale,
                              const float* __restrict__ col_scale,
                              const float* __restrict__ bias_shift,
                              unsigned short* __restrict__ WCT2,
                              float* __restrict__ bias2) {
  const int t = blockIdx.x * 256 + threadIdx.x;
  if (t < 512) {
    const int o = t >> 3, k = t & 7;
    bias2[t] = bias[t] + (k == 0 ? bias_shift[o] : 0.0f);
  }
  if (t >= 64 * 64) return;
  const int o = t >> 6, n = t & 63;  // n = input feature = kq
  const float rs = row_scale[o], cs = col_scale[n];
  float w[8];
#pragma unroll
  for (int j = 0; j < 8; ++j) {
    float v = weight[(size_t)t * 8 + j] * rs * cs;
    w[j] = (v != v) ? 0.0f : v;  // nan_to_num
  }
  constexpr int TI[64] = {0,1,2,3,4,5,6,7, 0,1,2,4,3,5,6,7, 0,2,1,4,3,6,5,7,
                          0,3,1,5,2,6,4,7, 0,4,1,2,3,7,5,6, 0,5,1,3,2,7,4,6,
                          0,6,2,3,1,7,4,5, 0,7,1,6,2,5,3,4};
  constexpr int TJ[64] = {0,1,2,3,4,5,6,7, 1,0,4,2,5,3,7,6, 2,0,4,1,6,3,7,5,
                          3,0,5,1,6,2,7,4, 4,0,2,1,7,3,6,5, 5,0,3,1,7,2,6,4,
                          6,0,3,2,7,1,5,4, 7,0,6,1,5,2,4,3};
  constexpr int TK[64] = {0,0,0,0,0,0,0,0, 1,1,1,1,1,1,1,1, 2,2,2,2,2,2,2,2,
                          3,3,3,3,3,3,3,3, 4,4,4,4,4,4,4,4, 5,5,5,5,5,5,5,5,
                          6,6,6,6,6,6,6,6, 7,7,7,7,7,7,7,7};
  constexpr float TS[64] = {1,1,1,1,-1,-1,-1,-1, 1,1,-1,1,-1,1,-1,-1, 1,1,1,-1,-1,1,1,1,
                            1,1,1,-1,1,-1,-1,-1, 1,1,1,-1,1,1,-1,1,  1,1,1,-1,-1,-1,1,-1,
                            1,1,1,-1,1,1,-1,1,   1,1,1,1,-1,-1,1,1};
  float wc[8][8];
#pragma unroll
  for (int i = 0; i < 8; ++i)
#pragma unroll
    for (int k = 0; k < 8; ++k) wc[i][k] = 0.0f;
#pragma unroll
  for (int e = 0; e < 64; ++e) wc[TI[e]][TK[e]] += TS[e] * w[TJ[e]];
#pragma unroll
  for (int kb = 0; kb < 8; ++kb)
#pragma unroll
    for (int i = 0; i < 8; ++i)
      WCT2[((size_t)n * N_DIM + o * 8 + kb) * 8 + i] = f2bf(wc[i][kb]);
}

// ---------------------------------------------------------------------------
// GEMM: out = x * W^T (+bias2). BARRIER-FREE. Waves are 2x2 (64x64 tiles);
// each wave privately stages its own 64-row A slice into its own LDS region:
//   global (DENSE: lane l -> tile-linear offset l*16, each instr = 8 rows x
//   128B = 8 full cache lines, zero redundancy) -> VGPR (depth-2) ->
//   cvt_pk bf16 -> ds_write_b64 -> ds_read_b128 fragments.
// No __syncthreads anywhere: in-wave DS ordering + waitcnts suffice.
// B direct from L2-resident WCT2 (1 ptr, imm offsets, dense 16B/lane).
// ---------------------------------------------------------------------------
__global__ __launch_bounds__(256, 2) void clifford_gemm(
    const float* __restrict__ x, const unsigned short* __restrict__ WCT2,
    const float* __restrict__ bias2, float* __restrict__ out) {
  __shared__ __align__(16) unsigned short As[2 * 4 * WREG];  // 33.3 KB

  const int tid = threadIdx.x;
  const int lane = tid & 63;
  const int wv = tid >> 6;

  const int bid = blockIdx.x;
  const int grp = bid >> 5, r = bid & 31;
  const size_t m0 = (size_t)(grp * 8 + (r & 7)) * BM;
  const int n0 = (r >> 3) * BN;

  const int wmv = (wv & 1) * 64;   // wave row offset in block tile
  const int wnv = (wv >> 1) * 64;  // wave col offset
  const int lm = lane & 15;
  const int kg = lane >> 4;  // 0..3

  // ---- A global: lane piece p covers row (lane>>3)+8p, f32-block lane&7 ----
  const int arow = lane >> 3;  // 0..7
  const int ablk = lane & 7;   // 0..7 (4 floats each)
  const float* aP[8];
#pragma unroll
  for (int p = 0; p < 8; ++p)
    aP[p] = x + (m0 + wmv + arow + 8 * p) * (size_t)K_DIM + ablk * 4;

  // ---- B global: one pointer, fragments at imm offsets ni*128 shorts ----
  const unsigned short* bg =
      WCT2 + ((size_t)kg * N_DIM + (n0 + wnv + lm)) * 8;

  // ---- LDS addressing (shorts). Region = (buf*4+wv)*WREG. ----
  // write piece p: kb=(ablk>>1) slab, row arow+8p, half (ablk&1)
  unsigned short* wr0 = &As[(0 * 4 + wv) * WREG + (ablk >> 1) * KBS + arow * 8 + (ablk & 1) * 4];
  unsigned short* wr1 = &As[(1 * 4 + wv) * WREG + (ablk >> 1) * KBS + arow * 8 + (ablk & 1) * 4];
  // read frag mi: slab kg, row mi*16+lm -> imm offset mi*256B
  const unsigned short* rd0 = &As[(0 * 4 + wv) * WREG + kg * KBS + lm * 8];
  const unsigned short* rd1 = &As[(1 * 4 + wv) * WREG + kg * KBS + lm * 8];

  const f32x4 zero = {0.f, 0.f, 0.f, 0.f};
  f32x4 acc[4][4];
#pragma unroll
  for (int i = 0; i < 4; ++i)
#pragma unroll
    for (int j = 0; j < 4; ++j) acc[i][j] = zero;

  f32x4 aR0[8], aR1[8];  // depth-2 A f32 staging
  us8 b0[4], b1[4];      // depth-2 B

  auto issueA = [&](f32x4 (&a)[8], int ks) {
#pragma unroll
    for (int p = 0; p < 8; ++p) a[p] = *(const f32x4*)(aP[p] + ks * BK);
  };
  auto loadB = [&](us8 (&bb)[4], int ks) {
    const unsigned short* p = bg + (size_t)ks * (4 * N_DIM * 8);
#pragma unroll
    for (int ni = 0; ni < 4; ++ni) bb[ni] = *(const us8*)(p + ni * 128);
  };
  auto cvtWrite = [&](f32x4 (&a)[8], unsigned short* wbase) {
#pragma unroll
    for (int p = 0; p < 8; ++p) {
      const unsigned int d0 = cvt_pk_bf16(a[p][0], a[p][1]);
      const unsigned int d1 = cvt_pk_bf16(a[p][2], a[p][3]);
      *(uint2*)(void*)(wbase + p * 64) = make_uint2(d0, d1);  // ds_write_b64
    }
  };

  // prologue
  issueA(aR0, 0);
  issueA(aR1, 1);
  loadB(b0, 0);
  loadB(b1, 1);
  cvtWrite(aR0, wr0);

  auto body = [&](int ks, int ODD, bool pf, bool docvt) {
    if (pf) issueA(ODD ? aR1 : aR0, ks + 2);  // overwrite set freed last iter
    const unsigned short* rb = ODD ? rd1 : rd0;
    bf16x8 af[4];
#pragma unroll
    for (int mi = 0; mi < 4; ++mi)
      af[mi] = __builtin_bit_cast(bf16x8, *(const us8*)(rb + mi * 128));
    us8(&bc)[4] = ODD ? b1 : b0;
#pragma unroll
    for (int mi = 0; mi < 4; ++mi)
#pragma unroll
      for (int ni = 0; ni < 4; ++ni)
        acc[mi][ni] = __builtin_amdgcn_mfma_f32_16x16x32_bf16(
            af[mi], __builtin_bit_cast(bf16x8, bc[ni]), acc[mi][ni], 0, 0, 0);
    if (docvt) cvtWrite(ODD ? aR0 : aR1, ODD ? wr0 : wr1);  // A(ks+1)->buf(!ODD)... parity: writes buf (ks+1)&1
    if (pf) loadB(ODD ? b1 : b0, ks + 2);
  };

  // steady state: ks = 0..13 all full; tails specialize flags
  for (int ks = 0; ks < KSTEPS - 2; ks += 2) {
    body(ks, 0, true, true);
    body(ks + 1, 1, true, true);
  }
  body(KSTEPS - 2, 0, false, true);
  body(KSTEPS - 1, 1, false, false);

  // epilogue: C/D layout col=lane&15 (n), row=(lane>>4)*4+reg (m)
#pragma unroll
  for (int ni = 0; ni < 4; ++ni) {
    const int nn = n0 + wnv + ni * 16 + lm;
    const float b2 = bias2[nn];
#pragma unroll
    for (int mi = 0; mi < 4; ++mi) {
#pragma unroll
      for (int rr = 0; rr < 4; ++rr) {
        const size_t mm = m0 + wmv + mi * 16 + kg * 4 + rr;
        out[mm * N_DIM + nn] = acc[mi][ni][rr] + b2;
      }
    }
  }
}

extern "C" void kernel_launch(void* const* d_in, const int* in_sizes, int n_in,
                              void* d_out, int out_size, void* d_ws, size_t ws_size,
                              hipStream_t stream) {
  const float* x          = (const float*)d_in[0];
  const float* weight     = (const float*)d_in[1];
  const float* bias       = (const float*)d_in[2];
  const float* row_scale  = (const float*)d_in[3];
  const float* col_scale  = (const float*)d_in[4];
  const float* bias_shift = (const float*)d_in[5];

  unsigned short* WCT2 = (unsigned short*)d_ws;                      // 512*512*2 B
  float* bias2 = (float*)((char*)d_ws + (size_t)N_DIM * K_DIM * 2);  // +2 KB

  clifford_prep<<<16, 256, 0, stream>>>(weight, bias, row_scale, col_scale,
                                        bias_shift, WCT2, bias2);
  clifford_gemm<<<(M_DIM / BM) * (N_DIM / BN), 256, 0, stream>>>(
      x, WCT2, bias2, (float*)d_out);
}

// Round 4
// 264.654 us; speedup vs baseline: 1.2454x; 1.0957x over previous
//
#include <hip/hip_runtime.h>
#include <cstdint>

#define M_DIM 65536
#define N_DIM 512
#define K_DIM 512
#define BM 128
#define BN 128
#define BK 32
#define KSTEPS 16
#define NRING 3
#define A_TILE_B (BM * BK * 4)       // 16384 B per f32 A-tile
#define B_TILE_B (4 * BN * 16)       // 8192 B per bf16 B-tile (4 kq x 128 n x 16B)
#define LDS_B_OFF (NRING * A_TILE_B) // 49152

typedef float f32x4 __attribute__((ext_vector_type(4)));
typedef __bf16 bf16x8 __attribute__((ext_vector_type(8)));
typedef unsigned short us8 __attribute__((ext_vector_type(8)));

__device__ __forceinline__ unsigned short f2bf(float f) {
  unsigned int u = __builtin_bit_cast(unsigned int, f);
  u += 0x7fffu + ((u >> 16) & 1u);  // round-to-nearest-even
  return (unsigned short)(u >> 16);
}

// packed f32x2 -> bf16x2 (RNE), 1 VALU op for 2 elements
__device__ __forceinline__ unsigned int cvt_pk_bf16(float lo, float hi) {
  unsigned int r;
  asm("v_cvt_pk_bf16_f32 %0, %1, %2" : "=v"(r) : "v"(lo), "v"(hi));
  return r;
}

__device__ __forceinline__ void async16(const void* g, void* l) {
  __builtin_amdgcn_global_load_lds(
      (const __attribute__((address_space(1))) void*)g,
      (__attribute__((address_space(3))) void*)l, 16, 0, 0);
}

// ---------------------------------------------------------------------------
// Prep: WCT2[(kq*512 + (o*8+kb))*8 + i] = bf16(wc[i][kb]) for (o, n_in=kq).
// ---------------------------------------------------------------------------
__global__ void clifford_prep(const float* __restrict__ weight,
                              const float* __restrict__ bias,
                              const float* __restrict__ row_scale,
                              const float* __restrict__ col_scale,
                              const float* __restrict__ bias_shift,
                              unsigned short* __restrict__ WCT2,
                              float* __restrict__ bias2) {
  const int t = blockIdx.x * 256 + threadIdx.x;
  if (t < 512) {
    const int o = t >> 3, k = t & 7;
    bias2[t] = bias[t] + (k == 0 ? bias_shift[o] : 0.0f);
  }
  if (t >= 64 * 64) return;
  const int o = t >> 6, n = t & 63;  // n = input feature = kq
  const float rs = row_scale[o], cs = col_scale[n];
  float w[8];
#pragma unroll
  for (int j = 0; j < 8; ++j) {
    float v = weight[(size_t)t * 8 + j] * rs * cs;
    w[j] = (v != v) ? 0.0f : v;  // nan_to_num
  }
  constexpr int TI[64] = {0,1,2,3,4,5,6,7, 0,1,2,4,3,5,6,7, 0,2,1,4,3,6,5,7,
                          0,3,1,5,2,6,4,7, 0,4,1,2,3,7,5,6, 0,5,1,3,2,7,4,6,
                          0,6,2,3,1,7,4,5, 0,7,1,6,2,5,3,4};
  constexpr int TJ[64] = {0,1,2,3,4,5,6,7, 1,0,4,2,5,3,7,6, 2,0,4,1,6,3,7,5,
                          3,0,5,1,6,2,7,4, 4,0,2,1,7,3,6,5, 5,0,3,1,7,2,6,4,
                          6,0,3,2,7,1,5,4, 7,0,6,1,5,2,4,3};
  constexpr int TK[64] = {0,0,0,0,0,0,0,0, 1,1,1,1,1,1,1,1, 2,2,2,2,2,2,2,2,
                          3,3,3,3,3,3,3,3, 4,4,4,4,4,4,4,4, 5,5,5,5,5,5,5,5,
                          6,6,6,6,6,6,6,6, 7,7,7,7,7,7,7,7};
  constexpr float TS[64] = {1,1,1,1,-1,-1,-1,-1, 1,1,-1,1,-1,1,-1,-1, 1,1,1,-1,-1,1,1,1,
                            1,1,1,-1,1,-1,-1,-1, 1,1,1,-1,1,1,-1,1,  1,1,1,-1,-1,-1,1,-1,
                            1,1,1,-1,1,1,-1,1,   1,1,1,1,-1,-1,1,1};
  float wc[8][8];
#pragma unroll
  for (int i = 0; i < 8; ++i)
#pragma unroll
    for (int k = 0; k < 8; ++k) wc[i][k] = 0.0f;
#pragma unroll
  for (int e = 0; e < 64; ++e) wc[TI[e]][TK[e]] += TS[e] * w[TJ[e]];
#pragma unroll
  for (int kb = 0; kb < 8; ++kb)
#pragma unroll
    for (int i = 0; i < 8; ++i)
      WCT2[((size_t)n * N_DIM + o * 8 + kb) * 8 + i] = f2bf(wc[i][kb]);
}

// ---------------------------------------------------------------------------
// GEMM: out = x * W^T (+bias2). Deep-pipelined (T3+T4): A(f32) and B(bf16)
// staged via global_load_lds into a 3-deep LDS ring; counted s_waitcnt
// vmcnt(12) in the main loop (never 0) keeps 2 tiles/block = 48 KB in flight
// across barriers -> ~96 KB/CU outstanding -> HBM-saturating (Little's law).
// A read with both-sides XOR swizzle (linear DMA dest, inverse-swizzled
// per-lane global source, swizzled read col). f32->bf16 via v_cvt_pk in regs.
// Per step: waitcnt(12); barrier; 12x ds_read_b128; cvt; 16 MFMA (setprio);
// barrier; issue tile ks+3 (6 async copies). 2 blocks/CU (72 KB LDS).
// ---------------------------------------------------------------------------
__global__ __launch_bounds__(256, 2) void clifford_gemm(
    const float* __restrict__ x, const unsigned short* __restrict__ WCT2,
    const float* __restrict__ bias2, float* __restrict__ out) {
  __shared__ __align__(16) char lds[NRING * A_TILE_B + NRING * B_TILE_B];  // 72 KB

  const int tid = threadIdx.x;
  const int lane = tid & 63;
  const int wv = tid >> 6;

  const int bid = blockIdx.x;
  const int grp = bid >> 5, r = bid & 31;
  const size_t m0 = (size_t)(grp * 8 + (r & 7)) * BM;
  const int n0 = (r >> 3) * BN;

  const int wm = (wv & 1) * 64;   // wave row offset
  const int wn = (wv >> 1) * 64;  // wave col offset
  const int lm = lane & 15;
  const int kg = lane >> 4;  // 0..3

  // ---- A DMA (4 copies/thread/tile): dest row = wv*32 + c*8 + (lane>>3),
  // dest col = (lane&7)*16, stored value must be x[row][col ^ ((row&7)<<4)]
  // -> per-lane source col = ((lane&7) ^ (lane>>3)) << 4.
  const int asw = ((lane & 7) ^ (lane >> 3)) << 4;
  const char* aSrc[4];
#pragma unroll
  for (int c = 0; c < 4; ++c)
    aSrc[c] = (const char*)x +
              (m0 + wv * 32 + c * 8 + (lane >> 3)) * (size_t)(K_DIM * 4) + asw;

  // ---- B DMA (2 copies/thread/tile): dest = c*4096 + wv*1024 + lane*16
  //   -> q = c*2 + (wv>>1), n_local = (wv&1)*64 + lane; source is 1KB-dense.
  const char* bSrc[2];
#pragma unroll
  for (int c = 0; c < 2; ++c) {
    const int q = c * 2 + (wv >> 1);
    const int nl = (wv & 1) * 64 + lane;
    bSrc[c] = (const char*)WCT2 + ((size_t)q * N_DIM + n0 + nl) * 16;
  }

  // ---- LDS read addresses ----
  // A frag(mi,h): byte = slot*16K + (wm+mi*16+lm)*128 + ((kg*32+h*16)^((lm&7)<<4))
  const int aRd0 = (wm + lm) * 128 + ((kg * 32 + 0) ^ ((lm & 7) << 4));
  const int aRd1 = (wm + lm) * 128 + ((kg * 32 + 16) ^ ((lm & 7) << 4));
  // B frag(ni): byte = LDS_B_OFF + slot*8K + kg*2048 + (wn+ni*16+lm)*16
  const int bRd = kg * 2048 + (wn + lm) * 16;

  const f32x4 zero = {0.f, 0.f, 0.f, 0.f};
  f32x4 acc[4][4];
#pragma unroll
  for (int i = 0; i < 4; ++i)
#pragma unroll
    for (int j = 0; j < 4; ++j) acc[i][j] = zero;

  auto issueTile = [&](int ks) {
    const int slot = ks % NRING;
    char* da = &lds[slot * A_TILE_B + wv * 4096];
#pragma unroll
    for (int c = 0; c < 4; ++c)
      async16(aSrc[c] + ks * (BK * 4), da + c * 1024);
    char* db = &lds[LDS_B_OFF + slot * B_TILE_B + wv * 1024];
#pragma unroll
    for (int c = 0; c < 2; ++c)
      async16(bSrc[c] + (size_t)ks * (4 * N_DIM * 16), db + c * 4096);
  };

  // prologue: fill the ring (18 copies in flight per thread)
  issueTile(0);
  issueTile(1);
  issueTile(2);

#pragma unroll
  for (int ks = 0; ks < KSTEPS; ++ks) {
    const int slot = ks % NRING;
    // counted wait: tiles > ks stay in flight (T4 - never drain in loop)
    if (ks < KSTEPS - 2)
      asm volatile("s_waitcnt vmcnt(12)" ::: "memory");
    else if (ks == KSTEPS - 2)
      asm volatile("s_waitcnt vmcnt(6)" ::: "memory");
    else
      asm volatile("s_waitcnt vmcnt(0)" ::: "memory");
    __builtin_amdgcn_s_barrier();

    f32x4 alo[4], ahi[4];
    us8 bfr[4];
#pragma unroll
    for (int mi = 0; mi < 4; ++mi) {
      alo[mi] = *(const f32x4*)&lds[slot * A_TILE_B + aRd0 + mi * 2048];
      ahi[mi] = *(const f32x4*)&lds[slot * A_TILE_B + aRd1 + mi * 2048];
    }
#pragma unroll
    for (int ni = 0; ni < 4; ++ni)
      bfr[ni] = *(const us8*)&lds[LDS_B_OFF + slot * B_TILE_B + bRd + ni * 256];

    bf16x8 af[4];
#pragma unroll
    for (int mi = 0; mi < 4; ++mi) {
      union { us8 v; unsigned int w[4]; } u;
      u.w[0] = cvt_pk_bf16(alo[mi][0], alo[mi][1]);
      u.w[1] = cvt_pk_bf16(alo[mi][2], alo[mi][3]);
      u.w[2] = cvt_pk_bf16(ahi[mi][0], ahi[mi][1]);
      u.w[3] = cvt_pk_bf16(ahi[mi][2], ahi[mi][3]);
      af[mi] = __builtin_bit_cast(bf16x8, u.v);
    }

    __builtin_amdgcn_s_setprio(1);
#pragma unroll
    for (int mi = 0; mi < 4; ++mi)
#pragma unroll
      for (int ni = 0; ni < 4; ++ni)
        acc[mi][ni] = __builtin_amdgcn_mfma_f32_16x16x32_bf16(
            af[mi], __builtin_bit_cast(bf16x8, bfr[ni]), acc[mi][ni], 0, 0, 0);
    __builtin_amdgcn_s_setprio(0);

    // all waves' ds_reads retired (lgkmcnt forced by MFMA deps) -> safe to
    // overwrite this ring slot after the barrier.
    __builtin_amdgcn_sched_barrier(0);
    __builtin_amdgcn_s_barrier();
    if (ks + NRING < KSTEPS) issueTile(ks + NRING);
  }

  // epilogue: C/D layout col=lane&15 (n), row=(lane>>4)*4+reg (m)
#pragma unroll
  for (int ni = 0; ni < 4; ++ni) {
    const int nn = n0 + wn + ni * 16 + lm;
    const float b2 = bias2[nn];
#pragma unroll
    for (int mi = 0; mi < 4; ++mi) {
#pragma unroll
      for (int rr = 0; rr < 4; ++rr) {
        const size_t mm = m0 + wm + mi * 16 + kg * 4 + rr;
        out[mm * N_DIM + nn] = acc[mi][ni][rr] + b2;
      }
    }
  }
}

extern "C" void kernel_launch(void* const* d_in, const int* in_sizes, int n_in,
                              void* d_out, int out_size, void* d_ws, size_t ws_size,
                              hipStream_t stream) {
  const float* x          = (const float*)d_in[0];
  const float* weight     = (const float*)d_in[1];
  const float* bias       = (const float*)d_in[2];
  const float* row_scale  = (const float*)d_in[3];
  const float* col_scale  = (const float*)d_in[4];
  const float* bias_shift = (const float*)d_in[5];

  unsigned short* WCT2 = (unsigned short*)d_ws;                      // 512*512*2 B
  float* bias2 = (float*)((char*)d_ws + (size_t)N_DIM * K_DIM * 2);  // +2 KB

  clifford_prep<<<16, 256, 0, stream>>>(weight, bias, row_scale, col_scale,
                                        bias_shift, WCT2, bias2);
  clifford_gemm<<<(M_DIM / BM) * (N_DIM / BN), 256, 0, stream>>>(
      x, WCT2, bias2, (float*)d_out);
}

// Round 5
// 262.614 us; speedup vs baseline: 1.2551x; 1.0078x over previous
//
#include <hip/hip_runtime.h>
#include <cstdint>

#define M_DIM 65536
#define N_DIM 512
#define K_DIM 512
#define BM 128
#define BN 128
#define BK 32
#define KSTEPS 16
#define NRING 2
#define A_TILE_B (BM * BK * 4)       // 16384 B per f32 A-tile
#define B_TILE_B (4 * BN * 16)       // 8192 B per bf16 B-tile (4 kq x 128 n x 16B)
#define LDS_B_OFF (NRING * A_TILE_B) // 32768

typedef float f32x4 __attribute__((ext_vector_type(4)));
typedef __bf16 bf16x8 __attribute__((ext_vector_type(8)));
typedef unsigned short us8 __attribute__((ext_vector_type(8)));

__device__ __forceinline__ unsigned short f2bf(float f) {
  unsigned int u = __builtin_bit_cast(unsigned int, f);
  u += 0x7fffu + ((u >> 16) & 1u);  // round-to-nearest-even
  return (unsigned short)(u >> 16);
}

// packed f32x2 -> bf16x2 (RNE), 1 VALU op for 2 elements
__device__ __forceinline__ unsigned int cvt_pk_bf16(float lo, float hi) {
  unsigned int r;
  asm("v_cvt_pk_bf16_f32 %0, %1, %2" : "=v"(r) : "v"(lo), "v"(hi));
  return r;
}

__device__ __forceinline__ void async16(const void* g, void* l) {
  __builtin_amdgcn_global_load_lds(
      (const __attribute__((address_space(1))) void*)g,
      (__attribute__((address_space(3))) void*)l, 16, 0, 0);
}

// ---------------------------------------------------------------------------
// Prep: WCT2[(kq*512 + (o*8+kb))*8 + i] = bf16(wc[i][kb]) for (o, n_in=kq).
// ---------------------------------------------------------------------------
__global__ void clifford_prep(const float* __restrict__ weight,
                              const float* __restrict__ bias,
                              const float* __restrict__ row_scale,
                              const float* __restrict__ col_scale,
                              const float* __restrict__ bias_shift,
                              unsigned short* __restrict__ WCT2,
                              float* __restrict__ bias2) {
  const int t = blockIdx.x * 256 + threadIdx.x;
  if (t < 512) {
    const int o = t >> 3, k = t & 7;
    bias2[t] = bias[t] + (k == 0 ? bias_shift[o] : 0.0f);
  }
  if (t >= 64 * 64) return;
  const int o = t >> 6, n = t & 63;  // n = input feature = kq
  const float rs = row_scale[o], cs = col_scale[n];
  float w[8];
#pragma unroll
  for (int j = 0; j < 8; ++j) {
    float v = weight[(size_t)t * 8 + j] * rs * cs;
    w[j] = (v != v) ? 0.0f : v;  // nan_to_num
  }
  constexpr int TI[64] = {0,1,2,3,4,5,6,7, 0,1,2,4,3,5,6,7, 0,2,1,4,3,6,5,7,
                          0,3,1,5,2,6,4,7, 0,4,1,2,3,7,5,6, 0,5,1,3,2,7,4,6,
                          0,6,2,3,1,7,4,5, 0,7,1,6,2,5,3,4};
  constexpr int TJ[64] = {0,1,2,3,4,5,6,7, 1,0,4,2,5,3,7,6, 2,0,4,1,6,3,7,5,
                          3,0,5,1,6,2,7,4, 4,0,2,1,7,3,6,5, 5,0,3,1,7,2,6,4,
                          6,0,3,2,7,1,5,4, 7,0,6,1,5,2,4,3};
  constexpr int TK[64] = {0,0,0,0,0,0,0,0, 1,1,1,1,1,1,1,1, 2,2,2,2,2,2,2,2,
                          3,3,3,3,3,3,3,3, 4,4,4,4,4,4,4,4, 5,5,5,5,5,5,5,5,
                          6,6,6,6,6,6,6,6, 7,7,7,7,7,7,7,7};
  constexpr float TS[64] = {1,1,1,1,-1,-1,-1,-1, 1,1,-1,1,-1,1,-1,-1, 1,1,1,-1,-1,1,1,1,
                            1,1,1,-1,1,-1,-1,-1, 1,1,1,-1,1,1,-1,1,  1,1,1,-1,-1,-1,1,-1,
                            1,1,1,-1,1,1,-1,1,   1,1,1,1,-1,-1,1,1};
  float wc[8][8];
#pragma unroll
  for (int i = 0; i < 8; ++i)
#pragma unroll
    for (int k = 0; k < 8; ++k) wc[i][k] = 0.0f;
#pragma unroll
  for (int e = 0; e < 64; ++e) wc[TI[e]][TK[e]] += TS[e] * w[TJ[e]];
#pragma unroll
  for (int kb = 0; kb < 8; ++kb)
#pragma unroll
    for (int i = 0; i < 8; ++i)
      WCT2[((size_t)n * N_DIM + o * 8 + kb) * 8 + i] = f2bf(wc[i][kb]);
}

// ---------------------------------------------------------------------------
// GEMM: out = x * W^T (+bias2). Deep-pipelined (T3+T4): A(f32) and B(bf16)
// staged via global_load_lds into a 2-deep LDS ring (48 KB -> 3 blocks/CU,
// 3 independent barrier groups per CU to pack the pipes); counted s_waitcnt
// vmcnt(6) in the main loop (never 0) keeps a full tile + fresh issues in
// flight across barriers. Issue->use distance = 2 steps >> HBM latency.
// A read with both-sides XOR swizzle (linear DMA dest, inverse-swizzled
// per-lane global source, swizzled read col). f32->bf16 via v_cvt_pk in regs.
// ---------------------------------------------------------------------------
__global__ __launch_bounds__(256, 3) void clifford_gemm(
    const float* __restrict__ x, const unsigned short* __restrict__ WCT2,
    const float* __restrict__ bias2, float* __restrict__ out) {
  __shared__ __align__(16) char lds[NRING * A_TILE_B + NRING * B_TILE_B];  // 48 KB

  const int tid = threadIdx.x;
  const int lane = tid & 63;
  const int wv = tid >> 6;

  const int bid = blockIdx.x;
  const int grp = bid >> 5, r = bid & 31;
  const size_t m0 = (size_t)(grp * 8 + (r & 7)) * BM;
  const int n0 = (r >> 3) * BN;

  const int wm = (wv & 1) * 64;   // wave row offset
  const int wn = (wv >> 1) * 64;  // wave col offset
  const int lm = lane & 15;
  const int kg = lane >> 4;  // 0..3

  // ---- A DMA (4 copies/thread/tile): dest row = wv*32 + c*8 + (lane>>3),
  // dest col = (lane&7)*16, stored value must be x[row][col ^ ((row&7)<<4)]
  // -> per-lane source col = ((lane&7) ^ (lane>>3)) << 4.
  const int asw = ((lane & 7) ^ (lane >> 3)) << 4;
  const char* aSrc[4];
#pragma unroll
  for (int c = 0; c < 4; ++c)
    aSrc[c] = (const char*)x +
              (m0 + wv * 32 + c * 8 + (lane >> 3)) * (size_t)(K_DIM * 4) + asw;

  // ---- B DMA (2 copies/thread/tile): dest = c*4096 + wv*1024 + lane*16
  //   -> q = c*2 + (wv>>1), n_local = (wv&1)*64 + lane; source is 1KB-dense.
  const char* bSrc[2];
#pragma unroll
  for (int c = 0; c < 2; ++c) {
    const int q = c * 2 + (wv >> 1);
    const int nl = (wv & 1) * 64 + lane;
    bSrc[c] = (const char*)WCT2 + ((size_t)q * N_DIM + n0 + nl) * 16;
  }

  // ---- LDS read addresses ----
  // A frag(mi,h): byte = slot*16K + (wm+mi*16+lm)*128 + ((kg*32+h*16)^((lm&7)<<4))
  const int aRd0 = (wm + lm) * 128 + ((kg * 32 + 0) ^ ((lm & 7) << 4));
  const int aRd1 = (wm + lm) * 128 + ((kg * 32 + 16) ^ ((lm & 7) << 4));
  // B frag(ni): byte = LDS_B_OFF + slot*8K + kg*2048 + (wn+ni*16+lm)*16
  const int bRd = kg * 2048 + (wn + lm) * 16;

  const f32x4 zero = {0.f, 0.f, 0.f, 0.f};
  f32x4 acc[4][4];
#pragma unroll
  for (int i = 0; i < 4; ++i)
#pragma unroll
    for (int j = 0; j < 4; ++j) acc[i][j] = zero;

  auto issueTile = [&](int ks) {
    const int slot = ks % NRING;
    char* da = &lds[slot * A_TILE_B + wv * 4096];
#pragma unroll
    for (int c = 0; c < 4; ++c)
      async16(aSrc[c] + ks * (BK * 4), da + c * 1024);
    char* db = &lds[LDS_B_OFF + slot * B_TILE_B + wv * 1024];
#pragma unroll
    for (int c = 0; c < 2; ++c)
      async16(bSrc[c] + (size_t)ks * (4 * N_DIM * 16), db + c * 4096);
  };

  // prologue: fill the ring (12 copies in flight per thread)
  issueTile(0);
  issueTile(1);

#pragma unroll
  for (int ks = 0; ks < KSTEPS; ++ks) {
    const int slot = ks % NRING;
    // counted wait: tile ks arrived, tile ks+1 (6 loads) stays in flight (T4)
    if (ks < KSTEPS - 1)
      asm volatile("s_waitcnt vmcnt(6)" ::: "memory");
    else
      asm volatile("s_waitcnt vmcnt(0)" ::: "memory");
    __builtin_amdgcn_s_barrier();

    f32x4 alo[4], ahi[4];
    us8 bfr[4];
#pragma unroll
    for (int mi = 0; mi < 4; ++mi) {
      alo[mi] = *(const f32x4*)&lds[slot * A_TILE_B + aRd0 + mi * 2048];
      ahi[mi] = *(const f32x4*)&lds[slot * A_TILE_B + aRd1 + mi * 2048];
    }
#pragma unroll
    for (int ni = 0; ni < 4; ++ni)
      bfr[ni] = *(const us8*)&lds[LDS_B_OFF + slot * B_TILE_B + bRd + ni * 256];

    bf16x8 af[4];
#pragma unroll
    for (int mi = 0; mi < 4; ++mi) {
      union { us8 v; unsigned int w[4]; } u;
      u.w[0] = cvt_pk_bf16(alo[mi][0], alo[mi][1]);
      u.w[1] = cvt_pk_bf16(alo[mi][2], alo[mi][3]);
      u.w[2] = cvt_pk_bf16(ahi[mi][0], ahi[mi][1]);
      u.w[3] = cvt_pk_bf16(ahi[mi][2], ahi[mi][3]);
      af[mi] = __builtin_bit_cast(bf16x8, u.v);
    }

    __builtin_amdgcn_s_setprio(1);
#pragma unroll
    for (int mi = 0; mi < 4; ++mi)
#pragma unroll
      for (int ni = 0; ni < 4; ++ni)
        acc[mi][ni] = __builtin_amdgcn_mfma_f32_16x16x32_bf16(
            af[mi], __builtin_bit_cast(bf16x8, bfr[ni]), acc[mi][ni], 0, 0, 0);
    __builtin_amdgcn_s_setprio(0);

    // all waves' ds_reads retired (lgkmcnt forced by cvt/MFMA deps) -> safe
    // to overwrite this ring slot after the barrier.
    __builtin_amdgcn_sched_barrier(0);
    __builtin_amdgcn_s_barrier();
    if (ks + NRING < KSTEPS) issueTile(ks + NRING);
  }

  // epilogue: C/D layout col=lane&15 (n), row=(lane>>4)*4+reg (m)
#pragma unroll
  for (int ni = 0; ni < 4; ++ni) {
    const int nn = n0 + wn + ni * 16 + lm;
    const float b2 = bias2[nn];
#pragma unroll
    for (int mi = 0; mi < 4; ++mi) {
#pragma unroll
      for (int rr = 0; rr < 4; ++rr) {
        const size_t mm = m0 + wm + mi * 16 + kg * 4 + rr;
        out[mm * N_DIM + nn] = acc[mi][ni][rr] + b2;
      }
    }
  }
}

extern "C" void kernel_launch(void* const* d_in, const int* in_sizes, int n_in,
                              void* d_out, int out_size, void* d_ws, size_t ws_size,
                              hipStream_t stream) {
  const float* x          = (const float*)d_in[0];
  const float* weight     = (const float*)d_in[1];
  const float* bias       = (const float*)d_in[2];
  const float* row_scale  = (const float*)d_in[3];
  const float* col_scale  = (const float*)d_in[4];
  const float* bias_shift = (const float*)d_in[5];

  unsigned short* WCT2 = (unsigned short*)d_ws;                      // 512*512*2 B
  float* bias2 = (float*)((char*)d_ws + (size_t)N_DIM * K_DIM * 2);  // +2 KB

  clifford_prep<<<16, 256, 0, stream>>>(weight, bias, row_scale, col_scale,
                                        bias_shift, WCT2, bias2);
  clifford_gemm<<<(M_DIM / BM) * (N_DIM / BN), 256, 0, stream>>>(
      x, WCT2, bias2, (float*)d_out);
}